// Round 1
// baseline (570.938 us; speedup 1.0000x reference)
//
#include <hip/hip_runtime.h>
#include <math.h>

#define B_ 256
#define A_ 196
#define R_ 1024
#define V_ 10000
#define G4 4096
#define M_ (B_ * A_)   // 50176

typedef __bf16 bf16x8 __attribute__((ext_vector_type(8)));
typedef float f32x4 __attribute__((ext_vector_type(4)));

// ws layout in floats (~21.8 MB)
#define OFF_ATTH   0
#define OFF_SCORE  50176
#define OFF_WEIGHT 100352
#define OFF_ATTRES 150528
#define OFF_P0     412672
#define OFF_P1     1461248
#define OFF_NHBF   2509824
#define OFF_LOGITS 2640896
#define OFF_PACKA  5200896   // a2a_w bf16 [208][1024]
#define OFF_PACKH  5307392   // h2a_w bf16 [256][1024]

__device__ __forceinline__ float tanh_fast(float x) {
    float e = __expf(2.f * x);
    return 1.f - 2.f / (e + 1.f);
}
__device__ __forceinline__ float sigmoid_fast(float x) {
    return 1.f / (1.f + __expf(-x));
}

__device__ __forceinline__ bf16x8 cvt8(float4 f0, float4 f1) {
    bf16x8 v;
    v[0] = (__bf16)f0.x; v[1] = (__bf16)f0.y; v[2] = (__bf16)f0.z; v[3] = (__bf16)f0.w;
    v[4] = (__bf16)f1.x; v[5] = (__bf16)f1.y; v[6] = (__bf16)f1.z; v[7] = (__bf16)f1.w;
    return v;
}

// ---------------- kernel 0: pack a2a_w and h2a_w to bf16 (zero-padded rows) ---
__global__ void pack_kernel(const float* __restrict__ a2a_w,
                            const float* __restrict__ h2a_w,
                            __bf16* __restrict__ packA,   // [208][1024]
                            __bf16* __restrict__ packH) { // [256][1024]
    int row = blockIdx.x;
    int c = threadIdx.x * 4;
    if (row < 208) {
        float4 f = (row < A_) ? *(const float4*)(a2a_w + (size_t)row * R_ + c)
                              : make_float4(0.f, 0.f, 0.f, 0.f);
        __bf16* p = packA + (size_t)row * R_ + c;
        p[0] = (__bf16)f.x; p[1] = (__bf16)f.y; p[2] = (__bf16)f.z; p[3] = (__bf16)f.w;
    } else {
        int r2 = row - 208;
        float4 f = (r2 < A_) ? *(const float4*)(h2a_w + (size_t)r2 * R_ + c)
                             : make_float4(0.f, 0.f, 0.f, 0.f);
        __bf16* p = packH + (size_t)r2 * R_ + c;
        p[0] = (__bf16)f.x; p[1] = (__bf16)f.y; p[2] = (__bf16)f.z; p[3] = (__bf16)f.w;
    }
}

// ---------------- kernel 1: att_h = prev_h @ h2a_w.T + h2a_b  (MFMA) ----------
__global__ __launch_bounds__(256)
void att_h_gemm(const float* __restrict__ prev_h,
                const __bf16* __restrict__ packH,
                const float* __restrict__ h2a_b,
                float* __restrict__ att_h) {
    __shared__ alignas(16) __bf16 As[64][40];
    __shared__ alignas(16) __bf16 Bs[64][40];
    int tid = threadIdx.x;
    int m0 = blockIdx.x * 64, n0 = blockIdx.y * 64;
    int lane = tid & 63, w = tid >> 6, ln = lane & 15, quad = lane >> 4;
    int arow = tid >> 2, akq = (tid & 3) * 8;

    f32x4 acc[4];
#pragma unroll
    for (int t = 0; t < 4; ++t) acc[t] = {0.f, 0.f, 0.f, 0.f};

    const float* Asrc = prev_h + (size_t)(m0 + arow) * R_ + akq;
    const __bf16* Bsrc = packH + (size_t)(n0 + arow) * R_ + akq;

    float4 pa0 = *(const float4*)Asrc;
    float4 pa1 = *(const float4*)(Asrc + 4);
    bf16x8 pb = *(const bf16x8*)Bsrc;

    for (int k0 = 0; k0 < R_; k0 += 32) {
        __syncthreads();
        *(bf16x8*)&As[arow][akq] = cvt8(pa0, pa1);
        *(bf16x8*)&Bs[arow][akq] = pb;
        __syncthreads();
        if (k0 + 32 < R_) {
            pa0 = *(const float4*)(Asrc + k0 + 32);
            pa1 = *(const float4*)(Asrc + k0 + 36);
            pb = *(const bf16x8*)(Bsrc + k0 + 32);
        }
        bf16x8 a = *(bf16x8*)&As[w * 16 + ln][quad * 8];
#pragma unroll
        for (int t = 0; t < 4; ++t) {
            bf16x8 b = *(bf16x8*)&Bs[t * 16 + ln][quad * 8];
            acc[t] = __builtin_amdgcn_mfma_f32_16x16x32_bf16(a, b, acc[t], 0, 0, 0);
        }
    }
#pragma unroll
    for (int t = 0; t < 4; ++t) {
#pragma unroll
        for (int r = 0; r < 4; ++r) {
            int m = m0 + w * 16 + quad * 4 + r;
            int n = n0 + t * 16 + ln;
            if (n < A_) att_h[m * A_ + n] = acc[t][r] + h2a_b[n];
        }
    }
}

// ---------------- kernel 2: attention GEMM + tanh/d2d epilogue -----------------
// Rewritten: A (att) direct-to-register (no cross-wave reuse -> no LDS),
// B (packA) via async global_load_lds into double-buffered LDS,
// raw s_barrier + counted s_waitcnt vmcnt(7) so next-phase loads stay in
// flight across the barrier (T3/T4-lite).
// LDS B layout: [256 rows][80 B] linear (40 bf16: 32 data + 8 pad).
// Fragment read byte = row*80 + quad*16 -> bank start (20*row+4*quad)%32:
// uniform 2-way alias over 16 lanes = free (m136).
__global__ __launch_bounds__(256)
void score_gemm_mfma(const float* __restrict__ att,
                     const __bf16* __restrict__ packA,  // a2a_w bf16 [208][1024]
                     const float* __restrict__ a2a_b,
                     const float* __restrict__ d2d_w,
                     const float* __restrict__ att_h,
                     float* __restrict__ score) {
    __shared__ alignas(16) char Bs[2][20480];   // 2 x 256 rows x 80 B = 40 KB
    int tid = threadIdx.x;
    int m0 = blockIdx.x * 64;
    int lane = tid & 63, w = tid >> 6, ln = lane & 15, quad = lane >> 4;

    // --- B staging precompute: 5 x 16B chunks per thread per phase ---
    // LDS byte o = (w*5+j)*1024 + lane*16 ; row = o/80 ; chunk ci = (o%80)/16
    // global src byte = row*2048 + k0*2 + ci*16   (ci==4 is pad, row>=208 is pad)
    const char* packAb = (const char*)packA;
    unsigned goff[5], loff[5];
#pragma unroll
    for (int j = 0; j < 5; ++j) {
        unsigned o = (unsigned)((w * 5 + j) * 1024 + lane * 16);
        unsigned row = o / 80u;
        unsigned ci = (o % 80u) / 16u;
        loff[j] = o;
        goff[j] = (row < 208u && ci < 4u) ? (row * 2048u + ci * 16u) : 0u;
    }

    // --- A: direct per-lane fragment pointer (row m0+w*16+ln, cols k0+quad*8..) ---
    const float* Ap = att + (size_t)(m0 + w * 16 + ln) * R_ + quad * 8;

    f32x4 acc[13];
#pragma unroll
    for (int t = 0; t < 13; ++t) acc[t] = {0.f, 0.f, 0.f, 0.f};

    // prologue: issue order = S(0)[5], A(0)[2], S(1)[5]  (regions split by asm)
#pragma unroll
    for (int j = 0; j < 5; ++j)
        __builtin_amdgcn_global_load_lds(
            (const __attribute__((address_space(1))) void*)(packAb + goff[j]),
            (__attribute__((address_space(3))) void*)(&Bs[0][0] + loff[j]), 16, 0, 0);
    asm volatile("" ::: "memory");
    float4 c0 = *(const float4*)Ap;
    float4 c1 = *(const float4*)(Ap + 4);
    asm volatile("" ::: "memory");
#pragma unroll
    for (int j = 0; j < 5; ++j)
        __builtin_amdgcn_global_load_lds(
            (const __attribute__((address_space(1))) void*)(packAb + goff[j] + 64),
            (__attribute__((address_space(3))) void*)(&Bs[1][0] + loff[j]), 16, 0, 0);
    asm volatile("" ::: "memory");

    // invariant entering phase p: outstanding (FIFO) = S(p)[5], A(p)[2], S(p+1)[5]
    for (int p = 0; p < 32; ++p) {
        int cur = p & 1;
        const char* bufc = &Bs[cur][0];
        float4 n0 = c0, n1 = c1;
        if (p + 1 < 32) {   // issue A(p+1)
            n0 = *(const float4*)(Ap + (p + 1) * 32);
            n1 = *(const float4*)(Ap + (p + 1) * 32 + 4);
        }
        if (p + 1 < 32)
            asm volatile("s_waitcnt vmcnt(7)" ::: "memory");  // S(p)+A(p) done
        else
            asm volatile("s_waitcnt vmcnt(0)" ::: "memory");  // drain tail
        bf16x8 a = cvt8(c0, c1);
        asm volatile("s_barrier" ::: "memory");   // all waves: buf[cur] staged
        const char* bp = bufc + ln * 80 + quad * 16;
#pragma unroll
        for (int t = 0; t < 13; ++t) {
            bf16x8 b = *(const bf16x8*)(bp + t * 1280);
            acc[t] = __builtin_amdgcn_mfma_f32_16x16x32_bf16(a, b, acc[t], 0, 0, 0);
        }
        c0 = n0; c1 = n1;
        asm volatile("s_barrier" ::: "memory");   // all waves done reading buf[cur]
        if (p + 2 < 32) {                          // stage S(p+2) into buf[cur]
            unsigned kb = (unsigned)(p + 2) * 64u;
#pragma unroll
            for (int j = 0; j < 5; ++j)
                __builtin_amdgcn_global_load_lds(
                    (const __attribute__((address_space(1))) void*)(packAb + goff[j] + kb),
                    (__attribute__((address_space(3))) void*)(bufc + loff[j]), 16, 0, 0);
        }
        asm volatile("" ::: "memory");
    }

    float wv[13], bb[13];
#pragma unroll
    for (int t = 0; t < 13; ++t) {
        int n = t * 16 + ln;
        wv[t] = (n < A_) ? d2d_w[n] : 0.f;
        bb[t] = (n < A_) ? a2a_b[n] : 0.f;
    }
#pragma unroll
    for (int r = 0; r < 4; ++r) {
        int m = m0 + w * 16 + quad * 4 + r;
        float ah = att_h[m];
        float p = 0.f;
#pragma unroll
        for (int t = 0; t < 13; ++t)
            p += tanh_fast(acc[t][r] + bb[t] + ah) * wv[t];
        p += __shfl_xor(p, 1);
        p += __shfl_xor(p, 2);
        p += __shfl_xor(p, 4);
        p += __shfl_xor(p, 8);
        if (ln == 0) score[m] = p;
    }
}

// ---------------- kernel 3: softmax over i per batch ---------------------------
__global__ void softmax_kernel(const float* __restrict__ score,
                               const float* __restrict__ d2d_b,
                               float* __restrict__ weight) {
    int b = blockIdx.x;
    int i = threadIdx.x;
    __shared__ float red[256];
    float sval = 0.f;
    float s = -1e30f;
    if (i < A_) {
        sval = score[b * A_ + i] + d2d_b[0];
        s = sval;
    }
    red[i] = s; __syncthreads();
    for (int off = 128; off > 0; off >>= 1) {
        if (i < off) red[i] = fmaxf(red[i], red[i + off]);
        __syncthreads();
    }
    float mx = red[0]; __syncthreads();
    float e = (i < A_) ? __expf(sval - mx) : 0.f;
    red[i] = e; __syncthreads();
    for (int off = 128; off > 0; off >>= 1) {
        if (i < off) red[i] += red[i + off];
        __syncthreads();
    }
    float inv = 1.f / red[0];
    if (i < A_) weight[b * A_ + i] = e * inv;
}

// ---------------- kernel 4: att_res[b,r] = sum_i att[b,i,r] * weight[b,i] ------
// grid (B, 2): each block does 512 cols -> 512 blocks, 8 waves/CU (was 4).
__global__ __launch_bounds__(256)
void att_res_kernel(const float* __restrict__ att,
                    const float* __restrict__ weight,
                    float* __restrict__ att_res) {
    int b = blockIdx.x;
    int r = blockIdx.y * 512 + threadIdx.x * 2;
    __shared__ float wsm[A_];
    if (threadIdx.x < A_) wsm[threadIdx.x] = weight[b * A_ + threadIdx.x];
    __syncthreads();
    const float* ap = att + (size_t)b * A_ * R_ + r;
    float acx = 0.f, acy = 0.f;
    for (int i = 0; i < A_; i += 4) {
        float2 v0 = *(const float2*)(ap + (size_t)(i + 0) * R_);
        float2 v1 = *(const float2*)(ap + (size_t)(i + 1) * R_);
        float2 v2 = *(const float2*)(ap + (size_t)(i + 2) * R_);
        float2 v3 = *(const float2*)(ap + (size_t)(i + 3) * R_);
        float w0 = wsm[i], w1 = wsm[i + 1], w2 = wsm[i + 2], w3 = wsm[i + 3];
        acx += v0.x * w0 + v1.x * w1 + v2.x * w2 + v3.x * w3;
        acy += v0.y * w0 + v1.y * w1 + v2.y * w2 + v3.y * w3;
    }
    *(float2*)(att_res + (size_t)b * R_ + r) = make_float2(acx, acy);
}

// ---------------- kernel 5: sums GEMM (MFMA, 3 phases, split-K=2) --------------
__global__ __launch_bounds__(256)
void sums_gemm_mfma(const float* __restrict__ x,
                    const float* __restrict__ prev_h,
                    const float* __restrict__ att_res,
                    const float* __restrict__ i2h_w,
                    const float* __restrict__ h2h_w,
                    const float* __restrict__ r2a_w,
                    float* __restrict__ P0,
                    float* __restrict__ P1) {
    __shared__ alignas(16) __bf16 As[64][40];
    __shared__ alignas(16) __bf16 Bs[64][40];
    int tid = threadIdx.x;
    int m0 = blockIdx.x * 64, n0 = blockIdx.y * 64;
    int ks = blockIdx.z;
    int kbeg = ks * 512, kend = kbeg + 512;
    int lane = tid & 63, w = tid >> 6, ln = lane & 15, quad = lane >> 4;
    int arow = tid >> 2, akq = (tid & 3) * 8;

    f32x4 acc[4];
#pragma unroll
    for (int t = 0; t < 4; ++t) acc[t] = {0.f, 0.f, 0.f, 0.f};

    const float* Al[3] = {x, prev_h, att_res};
    const float* Bl[3] = {i2h_w, h2h_w, r2a_w};
    for (int p = 0; p < 3; ++p) {
        const float* Asrc = Al[p] + (size_t)(m0 + arow) * R_ + akq;
        const float* Bsrc = Bl[p] + (size_t)(n0 + arow) * R_ + akq;
        float4 pa0 = *(const float4*)(Asrc + kbeg);
        float4 pa1 = *(const float4*)(Asrc + kbeg + 4);
        float4 pb0 = *(const float4*)(Bsrc + kbeg);
        float4 pb1 = *(const float4*)(Bsrc + kbeg + 4);
        for (int k0 = kbeg; k0 < kend; k0 += 32) {
            __syncthreads();
            *(bf16x8*)&As[arow][akq] = cvt8(pa0, pa1);
            *(bf16x8*)&Bs[arow][akq] = cvt8(pb0, pb1);
            __syncthreads();
            if (k0 + 32 < kend) {
                pa0 = *(const float4*)(Asrc + k0 + 32);
                pa1 = *(const float4*)(Asrc + k0 + 36);
                pb0 = *(const float4*)(Bsrc + k0 + 32);
                pb1 = *(const float4*)(Bsrc + k0 + 36);
            }
            bf16x8 a = *(bf16x8*)&As[w * 16 + ln][quad * 8];
#pragma unroll
            for (int t = 0; t < 4; ++t) {
                bf16x8 b = *(bf16x8*)&Bs[t * 16 + ln][quad * 8];
                acc[t] = __builtin_amdgcn_mfma_f32_16x16x32_bf16(a, b, acc[t], 0, 0, 0);
            }
        }
    }
    float* P = ks ? P1 : P0;
#pragma unroll
    for (int t = 0; t < 4; ++t) {
#pragma unroll
        for (int r = 0; r < 4; ++r) {
            int m = m0 + w * 16 + quad * 4 + r;
            int n = n0 + t * 16 + ln;
            P[(size_t)m * G4 + n] = acc[t][r];
        }
    }
}

// ---------------- kernel 6: LSTM gates ----------------------------------------
__global__ void gates_kernel(const float* __restrict__ P0,
                             const float* __restrict__ P1,
                             const float* __restrict__ i2h_b,
                             const float* __restrict__ h2h_b,
                             const float* __restrict__ r2a_b,
                             const float* __restrict__ prev_c,
                             float* __restrict__ out_c,
                             float* __restrict__ out_h,
                             __bf16* __restrict__ nh_bf) {
    int idx = blockIdx.x * 256 + threadIdx.x;
    int b = idx >> 10, r = idx & 1023;
    size_t off = (size_t)b * G4;
    float s0 = P0[off + r] + P1[off + r] + i2h_b[r] + h2h_b[r] + r2a_b[r];
    float s1 = P0[off + R_ + r] + P1[off + R_ + r] + i2h_b[R_ + r] + h2h_b[R_ + r] + r2a_b[R_ + r];
    float s2 = P0[off + 2 * R_ + r] + P1[off + 2 * R_ + r] + i2h_b[2 * R_ + r] + h2h_b[2 * R_ + r] + r2a_b[2 * R_ + r];
    float s3 = P0[off + 3 * R_ + r] + P1[off + 3 * R_ + r] + i2h_b[3 * R_ + r] + h2h_b[3 * R_ + r] + r2a_b[3 * R_ + r];
    float ig = sigmoid_fast(s0);
    float fg = sigmoid_fast(s1);
    float og = sigmoid_fast(s2);
    float it = tanh_fast(s3);
    float nc = fg * prev_c[idx] + ig * it;
    float nh = og * tanh_fast(nc);
    out_c[idx] = nc;
    out_h[idx] = nh;
    nh_bf[idx] = (__bf16)nh;
}

// ---------------- kernel 7: proj GEMM (MFMA) -----------------------------------
__global__ __launch_bounds__(256)
void proj_gemm_mfma(const __bf16* __restrict__ nh_bf,
                    const float* __restrict__ proj_w,
                    const float* __restrict__ proj_b,
                    float* __restrict__ logits) {
    __shared__ alignas(16) __bf16 As[64][40];
    __shared__ alignas(16) __bf16 Bs[64][40];
    int tid = threadIdx.x;
    int m0 = blockIdx.x * 64, n0 = blockIdx.y * 64;
    int lane = tid & 63, w = tid >> 6, ln = lane & 15, quad = lane >> 4;
    int arow = tid >> 2, akq = (tid & 3) * 8;

    f32x4 acc[4];
#pragma unroll
    for (int t = 0; t < 4; ++t) acc[t] = {0.f, 0.f, 0.f, 0.f};

    int nr = n0 + arow;
    int nrc = nr < V_ ? nr : V_ - 1;
    const __bf16* Asrc = nh_bf + (size_t)(m0 + arow) * R_ + akq;
    const float* Bsrc = proj_w + (size_t)nrc * R_ + akq;

    bf16x8 pa = *(const bf16x8*)Asrc;
    float4 pb0 = *(const float4*)Bsrc;
    float4 pb1 = *(const float4*)(Bsrc + 4);

    for (int k0 = 0; k0 < R_; k0 += 32) {
        __syncthreads();
        *(bf16x8*)&As[arow][akq] = pa;
        *(bf16x8*)&Bs[arow][akq] = cvt8(pb0, pb1);
        __syncthreads();
        if (k0 + 32 < R_) {
            pa = *(const bf16x8*)(Asrc + k0 + 32);
            pb0 = *(const float4*)(Bsrc + k0 + 32);
            pb1 = *(const float4*)(Bsrc + k0 + 36);
        }
        bf16x8 a = *(bf16x8*)&As[w * 16 + ln][quad * 8];
#pragma unroll
        for (int t = 0; t < 4; ++t) {
            bf16x8 b = *(bf16x8*)&Bs[t * 16 + ln][quad * 8];
            acc[t] = __builtin_amdgcn_mfma_f32_16x16x32_bf16(a, b, acc[t], 0, 0, 0);
        }
    }
#pragma unroll
    for (int t = 0; t < 4; ++t) {
#pragma unroll
        for (int r = 0; r < 4; ++r) {
            int m = m0 + w * 16 + quad * 4 + r;
            int n = n0 + t * 16 + ln;
            if (n < V_) logits[(size_t)m * V_ + n] = acc[t][r] + proj_b[n];
        }
    }
}

// ---------------- kernel 8: log_softmax over V per row -------------------------
__global__ void logsoftmax_kernel(const float* __restrict__ logits,
                                  float* __restrict__ out) {
    int b = blockIdx.x, t = threadIdx.x;
    __shared__ float red[256];
    const float* lp = logits + (size_t)b * V_;
    float mx = -1e30f;
    for (int v = t; v < V_; v += 256) mx = fmaxf(mx, lp[v]);
    red[t] = mx; __syncthreads();
    for (int off = 128; off > 0; off >>= 1) {
        if (t < off) red[t] = fmaxf(red[t], red[t + off]);
        __syncthreads();
    }
    mx = red[0]; __syncthreads();
    float s = 0.f;
    for (int v = t; v < V_; v += 256) s += __expf(lp[v] - mx);
    red[t] = s; __syncthreads();
    for (int off = 128; off > 0; off >>= 1) {
        if (t < off) red[t] += red[t + off];
        __syncthreads();
    }
    float lse = mx + __logf(red[0]);
    float* op = out + (size_t)b * V_;
    for (int v = t; v < V_; v += 256) op[v] = lp[v] - lse;
}

extern "C" void kernel_launch(void* const* d_in, const int* in_sizes, int n_in,
                              void* d_out, int out_size, void* d_ws, size_t ws_size,
                              hipStream_t stream) {
    const float* x      = (const float*)d_in[0];
    const float* att    = (const float*)d_in[1];
    const float* prev_c = (const float*)d_in[2];
    const float* prev_h = (const float*)d_in[3];
    const float* a2a_w  = (const float*)d_in[4];
    const float* a2a_b  = (const float*)d_in[5];
    const float* h2a_w  = (const float*)d_in[6];
    const float* h2a_b  = (const float*)d_in[7];
    const float* d2d_w  = (const float*)d_in[8];
    const float* d2d_b  = (const float*)d_in[9];
    const float* i2h_w  = (const float*)d_in[10];
    const float* i2h_b  = (const float*)d_in[11];
    const float* h2h_w  = (const float*)d_in[12];
    const float* h2h_b  = (const float*)d_in[13];
    const float* r2a_w  = (const float*)d_in[14];
    const float* r2a_b  = (const float*)d_in[15];
    const float* proj_w = (const float*)d_in[16];
    const float* proj_b = (const float*)d_in[17];

    float* ws      = (float*)d_ws;
    float* att_h   = ws + OFF_ATTH;
    float* score   = ws + OFF_SCORE;
    float* weight  = ws + OFF_WEIGHT;
    float* att_res = ws + OFF_ATTRES;
    float* P0      = ws + OFF_P0;
    float* P1      = ws + OFF_P1;
    __bf16* nh_bf  = (__bf16*)(ws + OFF_NHBF);
    float* logits  = ws + OFF_LOGITS;
    __bf16* packA  = (__bf16*)(ws + OFF_PACKA);
    __bf16* packH  = (__bf16*)(ws + OFF_PACKH);
    float* out     = (float*)d_out;

    pack_kernel<<<464, 256, 0, stream>>>(a2a_w, h2a_w, packA, packH);
    att_h_gemm<<<dim3(B_ / 64, 4), 256, 0, stream>>>(prev_h, packH, h2a_b, att_h);
    score_gemm_mfma<<<M_ / 64, 256, 0, stream>>>(att, packA, a2a_b, d2d_w, att_h, score);
    softmax_kernel<<<B_, 256, 0, stream>>>(score, d2d_b, weight);
    att_res_kernel<<<dim3(B_, 2), 256, 0, stream>>>(att, weight, att_res);
    sums_gemm_mfma<<<dim3(B_ / 64, G4 / 64, 2), 256, 0, stream>>>(
        x, prev_h, att_res, i2h_w, h2h_w, r2a_w, P0, P1);
    gates_kernel<<<(B_ * R_) / 256, 256, 0, stream>>>(
        P0, P1, i2h_b, h2h_b, r2a_b, prev_c, out, out + B_ * R_, nh_bf);
    proj_gemm_mfma<<<dim3(B_ / 64, (V_ + 63) / 64), 256, 0, stream>>>(
        nh_bf, proj_w, proj_b, logits);
    logsoftmax_kernel<<<B_, 256, 0, stream>>>(logits, out + 2 * B_ * R_);
}

// Round 2
// 555.347 us; speedup vs baseline: 1.0281x; 1.0281x over previous
//
#include <hip/hip_runtime.h>
#include <math.h>

#define B_ 256
#define A_ 196
#define R_ 1024
#define V_ 10000
#define G4 4096
#define M_ (B_ * A_)   // 50176

typedef __bf16 bf16x8 __attribute__((ext_vector_type(8)));
typedef float f32x4 __attribute__((ext_vector_type(4)));

// ws layout in floats (~21.8 MB)
#define OFF_ATTH   0
#define OFF_SCORE  50176
#define OFF_WEIGHT 100352
#define OFF_ATTRES 150528
#define OFF_P0     412672
#define OFF_P1     1461248
#define OFF_NHBF   2509824
#define OFF_LOGITS 2640896
#define OFF_PACKA  5200896   // a2a_w bf16 [208][1024]
#define OFF_PACKH  5307392   // h2a_w bf16 [256][1024]

__device__ __forceinline__ float tanh_fast(float x) {
    float e = __expf(2.f * x);
    return 1.f - 2.f / (e + 1.f);
}
__device__ __forceinline__ float sigmoid_fast(float x) {
    return 1.f / (1.f + __expf(-x));
}

__device__ __forceinline__ bf16x8 cvt8(float4 f0, float4 f1) {
    bf16x8 v;
    v[0] = (__bf16)f0.x; v[1] = (__bf16)f0.y; v[2] = (__bf16)f0.z; v[3] = (__bf16)f0.w;
    v[4] = (__bf16)f1.x; v[5] = (__bf16)f1.y; v[6] = (__bf16)f1.z; v[7] = (__bf16)f1.w;
    return v;
}

// ---------------- kernel 0: pack a2a_w and h2a_w to bf16 (zero-padded rows) ---
__global__ void pack_kernel(const float* __restrict__ a2a_w,
                            const float* __restrict__ h2a_w,
                            __bf16* __restrict__ packA,   // [208][1024]
                            __bf16* __restrict__ packH) { // [256][1024]
    int row = blockIdx.x;
    int c = threadIdx.x * 4;
    if (row < 208) {
        float4 f = (row < A_) ? *(const float4*)(a2a_w + (size_t)row * R_ + c)
                              : make_float4(0.f, 0.f, 0.f, 0.f);
        __bf16* p = packA + (size_t)row * R_ + c;
        p[0] = (__bf16)f.x; p[1] = (__bf16)f.y; p[2] = (__bf16)f.z; p[3] = (__bf16)f.w;
    } else {
        int r2 = row - 208;
        float4 f = (r2 < A_) ? *(const float4*)(h2a_w + (size_t)r2 * R_ + c)
                             : make_float4(0.f, 0.f, 0.f, 0.f);
        __bf16* p = packH + (size_t)r2 * R_ + c;
        p[0] = (__bf16)f.x; p[1] = (__bf16)f.y; p[2] = (__bf16)f.z; p[3] = (__bf16)f.w;
    }
}

// ---------------- kernel 1: att_h = prev_h @ h2a_w.T + h2a_b  (MFMA) ----------
__global__ __launch_bounds__(256)
void att_h_gemm(const float* __restrict__ prev_h,
                const __bf16* __restrict__ packH,
                const float* __restrict__ h2a_b,
                float* __restrict__ att_h) {
    __shared__ alignas(16) __bf16 As[64][40];
    __shared__ alignas(16) __bf16 Bs[64][40];
    int tid = threadIdx.x;
    int m0 = blockIdx.x * 64, n0 = blockIdx.y * 64;
    int lane = tid & 63, w = tid >> 6, ln = lane & 15, quad = lane >> 4;
    int arow = tid >> 2, akq = (tid & 3) * 8;

    f32x4 acc[4];
#pragma unroll
    for (int t = 0; t < 4; ++t) acc[t] = {0.f, 0.f, 0.f, 0.f};

    const float* Asrc = prev_h + (size_t)(m0 + arow) * R_ + akq;
    const __bf16* Bsrc = packH + (size_t)(n0 + arow) * R_ + akq;

    float4 pa0 = *(const float4*)Asrc;
    float4 pa1 = *(const float4*)(Asrc + 4);
    bf16x8 pb = *(const bf16x8*)Bsrc;

    for (int k0 = 0; k0 < R_; k0 += 32) {
        __syncthreads();
        *(bf16x8*)&As[arow][akq] = cvt8(pa0, pa1);
        *(bf16x8*)&Bs[arow][akq] = pb;
        __syncthreads();
        if (k0 + 32 < R_) {
            pa0 = *(const float4*)(Asrc + k0 + 32);
            pa1 = *(const float4*)(Asrc + k0 + 36);
            pb = *(const bf16x8*)(Bsrc + k0 + 32);
        }
        bf16x8 a = *(bf16x8*)&As[w * 16 + ln][quad * 8];
#pragma unroll
        for (int t = 0; t < 4; ++t) {
            bf16x8 b = *(bf16x8*)&Bs[t * 16 + ln][quad * 8];
            acc[t] = __builtin_amdgcn_mfma_f32_16x16x32_bf16(a, b, acc[t], 0, 0, 0);
        }
    }
#pragma unroll
    for (int t = 0; t < 4; ++t) {
#pragma unroll
        for (int r = 0; r < 4; ++r) {
            int m = m0 + w * 16 + quad * 4 + r;
            int n = n0 + t * 16 + ln;
            if (n < A_) att_h[m * A_ + n] = acc[t][r] + h2a_b[n];
        }
    }
}

// ---------------- kernel 2: attention GEMM + tanh/d2d epilogue -----------------
// A (att) direct-to-register with 4-PHASE-DEEP prefetch ring (static slots via
// unroll-by-4). B (packA) via global_load_lds double-buffered LDS.
// Uniform issue discipline (clamped tail addresses) keeps the per-wave VMEM
// FIFO invariant: instructions younger than S(p) at the wait point == 9
// (A(p+3)[2] + S(p+1)[5] + A(p+4)[2]), so s_waitcnt vmcnt(9) always
// guarantees S(p) and everything older has landed.
__global__ __launch_bounds__(256)
void score_gemm_mfma(const float* __restrict__ att,
                     const __bf16* __restrict__ packA,  // a2a_w bf16 [208][1024]
                     const float* __restrict__ a2a_b,
                     const float* __restrict__ d2d_w,
                     const float* __restrict__ att_h,
                     float* __restrict__ score) {
    __shared__ alignas(16) char Bs[2][20480];   // 2 x 256 rows x 80 B = 40 KB
    int tid = threadIdx.x;
    int m0 = blockIdx.x * 64;
    int lane = tid & 63, w = tid >> 6, ln = lane & 15, quad = lane >> 4;

    // --- B staging precompute: 5 x 16B chunks per thread per phase ---
    const char* packAb = (const char*)packA;
    unsigned goff[5], loff[5];
#pragma unroll
    for (int j = 0; j < 5; ++j) {
        unsigned o = (unsigned)((w * 5 + j) * 1024 + lane * 16);
        unsigned row = o / 80u;
        unsigned ci = (o % 80u) / 16u;
        loff[j] = o;
        goff[j] = (row < 208u && ci < 4u) ? (row * 2048u + ci * 16u) : 0u;
    }

    // --- A: per-lane fragment pointer (row m0+w*16+ln, cols quad*8 + p*32...) ---
    const float* Ap = att + (size_t)(m0 + w * 16 + ln) * R_ + quad * 8;

    f32x4 acc[13];
#pragma unroll
    for (int t = 0; t < 13; ++t) acc[t] = {0.f, 0.f, 0.f, 0.f};

    // ---- prologue: S(0), A(0), S(1), A(1), A(2), A(3) ----
#pragma unroll
    for (int j = 0; j < 5; ++j)
        __builtin_amdgcn_global_load_lds(
            (const __attribute__((address_space(1))) void*)(packAb + goff[j]),
            (__attribute__((address_space(3))) void*)(&Bs[0][0] + loff[j]), 16, 0, 0);
    asm volatile("" ::: "memory");
    float4 sa0_0 = *(const float4*)Ap;
    float4 sa0_1 = *(const float4*)(Ap + 4);
    asm volatile("" ::: "memory");
#pragma unroll
    for (int j = 0; j < 5; ++j)
        __builtin_amdgcn_global_load_lds(
            (const __attribute__((address_space(1))) void*)(packAb + goff[j] + 64),
            (__attribute__((address_space(3))) void*)(&Bs[1][0] + loff[j]), 16, 0, 0);
    asm volatile("" ::: "memory");
    float4 sa1_0 = *(const float4*)(Ap + 32);
    float4 sa1_1 = *(const float4*)(Ap + 36);
    float4 sa2_0 = *(const float4*)(Ap + 64);
    float4 sa2_1 = *(const float4*)(Ap + 68);
    float4 sa3_0 = *(const float4*)(Ap + 96);
    float4 sa3_1 = *(const float4*)(Ap + 100);
    asm volatile("" ::: "memory");

#define PHASE(J, S0, S1)                                                      \
    {                                                                         \
        int p = p4 + J;                                                       \
        bf16x8 a = cvt8(S0, S1);            /* consume A(p) before refill */  \
        int pn = p + 4; if (pn > 31) pn = 31;                                 \
        S0 = *(const float4*)(Ap + pn * 32);                                  \
        S1 = *(const float4*)(Ap + pn * 32 + 4);                              \
        asm volatile("" ::: "memory");                                        \
        asm volatile("s_waitcnt vmcnt(9)" ::: "memory");                      \
        asm volatile("s_barrier" ::: "memory");                               \
        const char* bp = &Bs[J & 1][0] + ln * 80 + quad * 16;                 \
        _Pragma("unroll")                                                     \
        for (int t = 0; t < 13; ++t) {                                        \
            bf16x8 b = *(const bf16x8*)(bp + t * 1280);                       \
            acc[t] = __builtin_amdgcn_mfma_f32_16x16x32_bf16(a, b, acc[t], 0, 0, 0); \
        }                                                                     \
        asm volatile("s_barrier" ::: "memory");                               \
        {                                                                     \
            int kp = p + 2; if (kp > 31) kp = 31;                             \
            unsigned kb = (unsigned)kp * 64u;                                 \
            char* dst = &Bs[J & 1][0];                                        \
            _Pragma("unroll")                                                 \
            for (int jj = 0; jj < 5; ++jj)                                    \
                __builtin_amdgcn_global_load_lds(                             \
                    (const __attribute__((address_space(1))) void*)(packAb + goff[jj] + kb), \
                    (__attribute__((address_space(3))) void*)(dst + loff[jj]), 16, 0, 0);    \
        }                                                                     \
        asm volatile("" ::: "memory");                                        \
    }

    for (int p4 = 0; p4 < 32; p4 += 4) {
        PHASE(0, sa0_0, sa0_1)
        PHASE(1, sa1_0, sa1_1)
        PHASE(2, sa2_0, sa2_1)
        PHASE(3, sa3_0, sa3_1)
    }
#undef PHASE

    float wv[13], bb[13];
#pragma unroll
    for (int t = 0; t < 13; ++t) {
        int n = t * 16 + ln;
        wv[t] = (n < A_) ? d2d_w[n] : 0.f;
        bb[t] = (n < A_) ? a2a_b[n] : 0.f;
    }
#pragma unroll
    for (int r = 0; r < 4; ++r) {
        int m = m0 + w * 16 + quad * 4 + r;
        float ah = att_h[m];
        float p = 0.f;
#pragma unroll
        for (int t = 0; t < 13; ++t)
            p += tanh_fast(acc[t][r] + bb[t] + ah) * wv[t];
        p += __shfl_xor(p, 1);
        p += __shfl_xor(p, 2);
        p += __shfl_xor(p, 4);
        p += __shfl_xor(p, 8);
        if (ln == 0) score[m] = p;
    }
}

// ---------------- kernel 3: softmax over i per batch ---------------------------
__global__ void softmax_kernel(const float* __restrict__ score,
                               const float* __restrict__ d2d_b,
                               float* __restrict__ weight) {
    int b = blockIdx.x;
    int i = threadIdx.x;
    __shared__ float red[256];
    float sval = 0.f;
    float s = -1e30f;
    if (i < A_) {
        sval = score[b * A_ + i] + d2d_b[0];
        s = sval;
    }
    red[i] = s; __syncthreads();
    for (int off = 128; off > 0; off >>= 1) {
        if (i < off) red[i] = fmaxf(red[i], red[i + off]);
        __syncthreads();
    }
    float mx = red[0]; __syncthreads();
    float e = (i < A_) ? __expf(sval - mx) : 0.f;
    red[i] = e; __syncthreads();
    for (int off = 128; off > 0; off >>= 1) {
        if (i < off) red[i] += red[i + off];
        __syncthreads();
    }
    float inv = 1.f / red[0];
    if (i < A_) weight[b * A_ + i] = e * inv;
}

// ---------------- kernel 4: att_res[b,r] = sum_i att[b,i,r] * weight[b,i] ------
__global__ __launch_bounds__(256)
void att_res_kernel(const float* __restrict__ att,
                    const float* __restrict__ weight,
                    float* __restrict__ att_res) {
    int b = blockIdx.x;
    int r = blockIdx.y * 512 + threadIdx.x * 2;
    __shared__ float wsm[A_];
    if (threadIdx.x < A_) wsm[threadIdx.x] = weight[b * A_ + threadIdx.x];
    __syncthreads();
    const float* ap = att + (size_t)b * A_ * R_ + r;
    float acx = 0.f, acy = 0.f;
    for (int i = 0; i < A_; i += 4) {
        float2 v0 = *(const float2*)(ap + (size_t)(i + 0) * R_);
        float2 v1 = *(const float2*)(ap + (size_t)(i + 1) * R_);
        float2 v2 = *(const float2*)(ap + (size_t)(i + 2) * R_);
        float2 v3 = *(const float2*)(ap + (size_t)(i + 3) * R_);
        float w0 = wsm[i], w1 = wsm[i + 1], w2 = wsm[i + 2], w3 = wsm[i + 3];
        acx += v0.x * w0 + v1.x * w1 + v2.x * w2 + v3.x * w3;
        acy += v0.y * w0 + v1.y * w1 + v2.y * w2 + v3.y * w3;
    }
    *(float2*)(att_res + (size_t)b * R_ + r) = make_float2(acx, acy);
}

// ---------------- kernel 5: sums GEMM (MFMA, 3 phases, split-K=2) --------------
__global__ __launch_bounds__(256)
void sums_gemm_mfma(const float* __restrict__ x,
                    const float* __restrict__ prev_h,
                    const float* __restrict__ att_res,
                    const float* __restrict__ i2h_w,
                    const float* __restrict__ h2h_w,
                    const float* __restrict__ r2a_w,
                    float* __restrict__ P0,
                    float* __restrict__ P1) {
    __shared__ alignas(16) __bf16 As[64][40];
    __shared__ alignas(16) __bf16 Bs[64][40];
    int tid = threadIdx.x;
    int m0 = blockIdx.x * 64, n0 = blockIdx.y * 64;
    int ks = blockIdx.z;
    int kbeg = ks * 512, kend = kbeg + 512;
    int lane = tid & 63, w = tid >> 6, ln = lane & 15, quad = lane >> 4;
    int arow = tid >> 2, akq = (tid & 3) * 8;

    f32x4 acc[4];
#pragma unroll
    for (int t = 0; t < 4; ++t) acc[t] = {0.f, 0.f, 0.f, 0.f};

    const float* Al[3] = {x, prev_h, att_res};
    const float* Bl[3] = {i2h_w, h2h_w, r2a_w};
    for (int p = 0; p < 3; ++p) {
        const float* Asrc = Al[p] + (size_t)(m0 + arow) * R_ + akq;
        const float* Bsrc = Bl[p] + (size_t)(n0 + arow) * R_ + akq;
        float4 pa0 = *(const float4*)(Asrc + kbeg);
        float4 pa1 = *(const float4*)(Asrc + kbeg + 4);
        float4 pb0 = *(const float4*)(Bsrc + kbeg);
        float4 pb1 = *(const float4*)(Bsrc + kbeg + 4);
        for (int k0 = kbeg; k0 < kend; k0 += 32) {
            __syncthreads();
            *(bf16x8*)&As[arow][akq] = cvt8(pa0, pa1);
            *(bf16x8*)&Bs[arow][akq] = cvt8(pb0, pb1);
            __syncthreads();
            if (k0 + 32 < kend) {
                pa0 = *(const float4*)(Asrc + k0 + 32);
                pa1 = *(const float4*)(Asrc + k0 + 36);
                pb0 = *(const float4*)(Bsrc + k0 + 32);
                pb1 = *(const float4*)(Bsrc + k0 + 36);
            }
            bf16x8 a = *(bf16x8*)&As[w * 16 + ln][quad * 8];
#pragma unroll
            for (int t = 0; t < 4; ++t) {
                bf16x8 b = *(bf16x8*)&Bs[t * 16 + ln][quad * 8];
                acc[t] = __builtin_amdgcn_mfma_f32_16x16x32_bf16(a, b, acc[t], 0, 0, 0);
            }
        }
    }
    float* P = ks ? P1 : P0;
#pragma unroll
    for (int t = 0; t < 4; ++t) {
#pragma unroll
        for (int r = 0; r < 4; ++r) {
            int m = m0 + w * 16 + quad * 4 + r;
            int n = n0 + t * 16 + ln;
            P[(size_t)m * G4 + n] = acc[t][r];
        }
    }
}

// ---------------- kernel 6: LSTM gates ----------------------------------------
__global__ void gates_kernel(const float* __restrict__ P0,
                             const float* __restrict__ P1,
                             const float* __restrict__ i2h_b,
                             const float* __restrict__ h2h_b,
                             const float* __restrict__ r2a_b,
                             const float* __restrict__ prev_c,
                             float* __restrict__ out_c,
                             float* __restrict__ out_h,
                             __bf16* __restrict__ nh_bf) {
    int idx = blockIdx.x * 256 + threadIdx.x;
    int b = idx >> 10, r = idx & 1023;
    size_t off = (size_t)b * G4;
    float s0 = P0[off + r] + P1[off + r] + i2h_b[r] + h2h_b[r] + r2a_b[r];
    float s1 = P0[off + R_ + r] + P1[off + R_ + r] + i2h_b[R_ + r] + h2h_b[R_ + r] + r2a_b[R_ + r];
    float s2 = P0[off + 2 * R_ + r] + P1[off + 2 * R_ + r] + i2h_b[2 * R_ + r] + h2h_b[2 * R_ + r] + r2a_b[2 * R_ + r];
    float s3 = P0[off + 3 * R_ + r] + P1[off + 3 * R_ + r] + i2h_b[3 * R_ + r] + h2h_b[3 * R_ + r] + r2a_b[3 * R_ + r];
    float ig = sigmoid_fast(s0);
    float fg = sigmoid_fast(s1);
    float og = sigmoid_fast(s2);
    float it = tanh_fast(s3);
    float nc = fg * prev_c[idx] + ig * it;
    float nh = og * tanh_fast(nc);
    out_c[idx] = nc;
    out_h[idx] = nh;
    nh_bf[idx] = (__bf16)nh;
}

// ---------------- kernel 7: proj GEMM (MFMA) -----------------------------------
__global__ __launch_bounds__(256)
void proj_gemm_mfma(const __bf16* __restrict__ nh_bf,
                    const float* __restrict__ proj_w,
                    const float* __restrict__ proj_b,
                    float* __restrict__ logits) {
    __shared__ alignas(16) __bf16 As[64][40];
    __shared__ alignas(16) __bf16 Bs[64][40];
    int tid = threadIdx.x;
    int m0 = blockIdx.x * 64, n0 = blockIdx.y * 64;
    int lane = tid & 63, w = tid >> 6, ln = lane & 15, quad = lane >> 4;
    int arow = tid >> 2, akq = (tid & 3) * 8;

    f32x4 acc[4];
#pragma unroll
    for (int t = 0; t < 4; ++t) acc[t] = {0.f, 0.f, 0.f, 0.f};

    int nr = n0 + arow;
    int nrc = nr < V_ ? nr : V_ - 1;
    const __bf16* Asrc = nh_bf + (size_t)(m0 + arow) * R_ + akq;
    const float* Bsrc = proj_w + (size_t)nrc * R_ + akq;

    bf16x8 pa = *(const bf16x8*)Asrc;
    float4 pb0 = *(const float4*)Bsrc;
    float4 pb1 = *(const float4*)(Bsrc + 4);

    for (int k0 = 0; k0 < R_; k0 += 32) {
        __syncthreads();
        *(bf16x8*)&As[arow][akq] = pa;
        *(bf16x8*)&Bs[arow][akq] = cvt8(pb0, pb1);
        __syncthreads();
        if (k0 + 32 < R_) {
            pa = *(const bf16x8*)(Asrc + k0 + 32);
            pb0 = *(const float4*)(Bsrc + k0 + 32);
            pb1 = *(const float4*)(Bsrc + k0 + 36);
        }
        bf16x8 a = *(bf16x8*)&As[w * 16 + ln][quad * 8];
#pragma unroll
        for (int t = 0; t < 4; ++t) {
            bf16x8 b = *(bf16x8*)&Bs[t * 16 + ln][quad * 8];
            acc[t] = __builtin_amdgcn_mfma_f32_16x16x32_bf16(a, b, acc[t], 0, 0, 0);
        }
    }
#pragma unroll
    for (int t = 0; t < 4; ++t) {
#pragma unroll
        for (int r = 0; r < 4; ++r) {
            int m = m0 + w * 16 + quad * 4 + r;
            int n = n0 + t * 16 + ln;
            if (n < V_) logits[(size_t)m * V_ + n] = acc[t][r] + proj_b[n];
        }
    }
}

// ---------------- kernel 8: log_softmax over V per row -------------------------
__global__ void logsoftmax_kernel(const float* __restrict__ logits,
                                  float* __restrict__ out) {
    int b = blockIdx.x, t = threadIdx.x;
    __shared__ float red[256];
    const float* lp = logits + (size_t)b * V_;
    float mx = -1e30f;
    for (int v = t; v < V_; v += 256) mx = fmaxf(mx, lp[v]);
    red[t] = mx; __syncthreads();
    for (int off = 128; off > 0; off >>= 1) {
        if (t < off) red[t] = fmaxf(red[t], red[t + off]);
        __syncthreads();
    }
    mx = red[0]; __syncthreads();
    float s = 0.f;
    for (int v = t; v < V_; v += 256) s += __expf(lp[v] - mx);
    red[t] = s; __syncthreads();
    for (int off = 128; off > 0; off >>= 1) {
        if (t < off) red[t] += red[t + off];
        __syncthreads();
    }
    float lse = mx + __logf(red[0]);
    float* op = out + (size_t)b * V_;
    for (int v = t; v < V_; v += 256) op[v] = lp[v] - lse;
}

extern "C" void kernel_launch(void* const* d_in, const int* in_sizes, int n_in,
                              void* d_out, int out_size, void* d_ws, size_t ws_size,
                              hipStream_t stream) {
    const float* x      = (const float*)d_in[0];
    const float* att    = (const float*)d_in[1];
    const float* prev_c = (const float*)d_in[2];
    const float* prev_h = (const float*)d_in[3];
    const float* a2a_w  = (const float*)d_in[4];
    const float* a2a_b  = (const float*)d_in[5];
    const float* h2a_w  = (const float*)d_in[6];
    const float* h2a_b  = (const float*)d_in[7];
    const float* d2d_w  = (const float*)d_in[8];
    const float* d2d_b  = (const float*)d_in[9];
    const float* i2h_w  = (const float*)d_in[10];
    const float* i2h_b  = (const float*)d_in[11];
    const float* h2h_w  = (const float*)d_in[12];
    const float* h2h_b  = (const float*)d_in[13];
    const float* r2a_w  = (const float*)d_in[14];
    const float* r2a_b  = (const float*)d_in[15];
    const float* proj_w = (const float*)d_in[16];
    const float* proj_b = (const float*)d_in[17];

    float* ws      = (float*)d_ws;
    float* att_h   = ws + OFF_ATTH;
    float* score   = ws + OFF_SCORE;
    float* weight  = ws + OFF_WEIGHT;
    float* att_res = ws + OFF_ATTRES;
    float* P0      = ws + OFF_P0;
    float* P1      = ws + OFF_P1;
    __bf16* nh_bf  = (__bf16*)(ws + OFF_NHBF);
    float* logits  = ws + OFF_LOGITS;
    __bf16* packA  = (__bf16*)(ws + OFF_PACKA);
    __bf16* packH  = (__bf16*)(ws + OFF_PACKH);
    float* out     = (float*)d_out;

    pack_kernel<<<464, 256, 0, stream>>>(a2a_w, h2a_w, packA, packH);
    att_h_gemm<<<dim3(B_ / 64, 4), 256, 0, stream>>>(prev_h, packH, h2a_b, att_h);
    score_gemm_mfma<<<M_ / 64, 256, 0, stream>>>(att, packA, a2a_b, d2d_w, att_h, score);
    softmax_kernel<<<B_, 256, 0, stream>>>(score, d2d_b, weight);
    att_res_kernel<<<dim3(B_, 2), 256, 0, stream>>>(att, weight, att_res);
    sums_gemm_mfma<<<dim3(B_ / 64, G4 / 64, 2), 256, 0, stream>>>(
        x, prev_h, att_res, i2h_w, h2h_w, r2a_w, P0, P1);
    gates_kernel<<<(B_ * R_) / 256, 256, 0, stream>>>(
        P0, P1, i2h_b, h2h_b, r2a_b, prev_c, out, out + B_ * R_, nh_bf);
    proj_gemm_mfma<<<dim3(B_ / 64, (V_ + 63) / 64), 256, 0, stream>>>(
        nh_bf, proj_w, proj_b, logits);
    logsoftmax_kernel<<<B_, 256, 0, stream>>>(logits, out + 2 * B_ * R_);
}